// Round 6
// baseline (532.401 us; speedup 1.0000x reference)
//
#include <hip/hip_runtime.h>

#define NVN 20000
#define NCN 20000
#define NE  500000
#define HID 64
#define NLAYER 3
#define TN 16      // nodes per MLP tile (grid 1250 -> ~5 waves/SIMD)
#define BSH 8      // bin shift: 256 nodes/bin
#define NB 79      // ceil(20000/256) bins
#define CAPSH 14   // bin capacity 16384 (avg fill 6329, 2.6x margin)
#define CAP (1 << CAPSH)
#define NBCAP (NB * CAP)
#define P1E 2048   // edges per scatter block -> 245 blocks

__device__ __forceinline__ float relu_(float x) { return fmaxf(x, 0.0f); }

// ---------------- bincur init: bin b allocates from b*CAP ------------------
__global__ __launch_bounds__(256) void bininit_kernel(
    int* __restrict__ bincurA, int* __restrict__ bincurB)
{
    int t = threadIdx.x;
    if (t < NB) { bincurA[t] = t << CAPSH; bincurB[t] = t << CAPSH; }
}

// ---------------- Binned scatter pass 1: edges -> bin-staged ----------------
// stage element: (src | dst<<16, bitcast(w)); both < 2^16. Bins are
// fixed-capacity (CAP) segments; blocks allocate via atomicAdd on bincur.
__global__ __launch_bounds__(256) void scatter_p1_kernel(
    const int* __restrict__ eiA, const float* __restrict__ ewA,
    int* __restrict__ bincurA, int2* __restrict__ stageA,
    const int* __restrict__ eiB, const float* __restrict__ ewB,
    int* __restrict__ bincurB, int2* __restrict__ stageB)
{
    __shared__ int rnk[P1E];            // 8 KB
    __shared__ int cnt[NB], base_[NB];
    int t = threadIdx.x;
    int e0 = blockIdx.x * P1E;

    for (int g = 0; g < 2; ++g) {
        const int* ei   = g ? eiB : eiA;
        const float* ew = g ? ewB : ewA;
        int* bincur     = g ? bincurB : bincurA;
        int2* stage     = g ? stageB : stageA;

        if (t < NB) cnt[t] = 0;
        __syncthreads();
        for (int i = t; i < P1E; i += 256) {
            int e = e0 + i;
            if (e < NE) {
                int d = ei[NE + e];
                rnk[i] = atomicAdd(&cnt[d >> BSH], 1);
            }
        }
        __syncthreads();
        if (t < NB && cnt[t] > 0) base_[t] = atomicAdd(&bincur[t], cnt[t]);
        __syncthreads();
        for (int i = t; i < P1E; i += 256) {
            int e = e0 + i;
            if (e < NE) {
                int s = ei[e], d = ei[NE + e];
                float w = ew[e];
                stage[base_[d >> BSH] + rnk[i]] =
                    make_int2((int)((unsigned)s | ((unsigned)d << 16)), __float_as_int(w));
            }
        }
        __syncthreads();
    }
}

// ---------------- Pass 2: LDS counting sort per bin ------------------------
// one block per (graph, bin); bin b occupies [b*CAP, bincur[b]) in stage.
// pair[] keeps the same gapped layout (per-node ranges are contiguous; the
// inter-bin gaps are never dereferenced). rowend[] replaces rowptr[n+1].
__global__ __launch_bounds__(1024) void scatter_p2_kernel(
    const int* __restrict__ bincurA, const int2* __restrict__ stageA,
    int* __restrict__ rowptrA, int* __restrict__ rowendA, int2* __restrict__ pairA,
    const int* __restrict__ bincurB, const int2* __restrict__ stageB,
    int* __restrict__ rowptrB, int* __restrict__ rowendB, int2* __restrict__ pairB)
{
    __shared__ int deg[256], pfx[256], cur[256];
    int g = blockIdx.x / NB;
    int b = blockIdx.x % NB;
    const int* bincur  = g ? bincurB : bincurA;
    const int2* stage  = g ? stageB : stageA;
    int* rowptr        = g ? rowptrB : rowptrA;
    int* rowend        = g ? rowendB : rowendA;
    int2* pair         = g ? pairB : pairA;

    int d0 = b << BSH;
    int d1 = min(d0 + 256, NCN);   // NVN == NCN
    int nd = d1 - d0;
    int t = threadIdx.x;
    int estart = b << CAPSH;
    int eend = bincur[b];

    if (t < 256) deg[t] = 0;
    __syncthreads();
    for (int e = estart + t; e < eend; e += 1024) {
        int dst = (int)((unsigned)stage[e].x >> 16);
        atomicAdd(&deg[dst - d0], 1);
    }
    __syncthreads();
    if (t < 256) pfx[t] = deg[t];
    __syncthreads();
    for (int off = 1; off < 256; off <<= 1) {
        int v = (t >= off && t < 256) ? pfx[t - off] : 0;
        __syncthreads();
        if (t < 256) pfx[t] += v;
        __syncthreads();
    }
    if (t < nd) {
        int ex = estart + pfx[t] - deg[t];   // exclusive
        rowptr[d0 + t] = ex;
        rowend[d0 + t] = estart + pfx[t];
        cur[t] = ex;
    }
    __syncthreads();
    for (int e = estart + t; e < eend; e += 1024) {
        int2 s = stage[e];
        unsigned u = (unsigned)s.x;
        int src = (int)(u & 0xFFFFu);
        int dst = (int)(u >> 16);
        int p = atomicAdd(&cur[dst - d0], 1);
        pair[p] = make_int2(src, s.y);
    }
}

// ---------------- Encoders (both node sets in one dispatch) ----------------
__global__ __launch_bounds__(256) void encode2_kernel(
    const float* __restrict__ xv, const float* __restrict__ pev,
    const float* __restrict__ ewv, const float* __restrict__ ebv,
    const float* __restrict__ pw1v, const float* __restrict__ pb1v,
    const float* __restrict__ pw2v, const float* __restrict__ pb2v,
    const float* __restrict__ xc, const float* __restrict__ pec,
    const float* __restrict__ ewc, const float* __restrict__ ebc,
    const float* __restrict__ pw1c, const float* __restrict__ pb1c,
    const float* __restrict__ pw2c, const float* __restrict__ pb2c,
    float* __restrict__ outv, float* __restrict__ outc)
{
    __shared__ float sh[4][64];
    const int VB = (NVN + 3) / 4;
    int wave = threadIdx.x >> 6, lane = threadIdx.x & 63;
    int b = blockIdx.x;
    bool isC = (b >= VB);
    const float* x   = isC ? xc : xv;
    const float* pe  = isC ? pec : pev;
    const float* ew  = isC ? ewc : ewv;
    const float* eb  = isC ? ebc : ebv;
    const float* pw1 = isC ? pw1c : pw1v;
    const float* pb1 = isC ? pb1c : pb1v;
    const float* pw2 = isC ? pw2c : pw2v;
    const float* pb2 = isC ? pb2c : pb2v;
    float* out = isC ? outc : outv;
    int N = isC ? NCN : NVN;
    int n = (isC ? b - VB : b) * 4 + wave;
    if (n >= N) return;

    float accp = pb1[lane], accm = accp;
#pragma unroll
    for (int k = 0; k < 8; ++k) {
        float p = pe[n * 8 + k];
        float w = pw1[k * 64 + lane];
        accp += p * w;
        accm -= p * w;
    }
    float hs = 0.5f * (relu_(accp) + relu_(accm));
    float* my = sh[wave];
    my[lane] = hs;
    __builtin_amdgcn_wave_barrier();

    int col = lane & 31;
    float peo = pb2[col];
#pragma unroll
    for (int k = 0; k < 64; k += 4) {
        float4 hv = *(const float4*)(my + k);
        peo = fmaf(hv.x, pw2[(k + 0) * 32 + col], peo);
        peo = fmaf(hv.y, pw2[(k + 1) * 32 + col], peo);
        peo = fmaf(hv.z, pw2[(k + 2) * 32 + col], peo);
        peo = fmaf(hv.w, pw2[(k + 3) * 32 + col], peo);
    }
    float lino = x[n * 2 + 0] * ew[col] + x[n * 2 + 1] * ew[32 + col] + eb[col];
    float h = (lane < 32) ? lino : peo;
    out[n * 64 + lane] = relu_(h);
}

// ---------------- Edge aggregation: R2's proven 16-deep pipeline -----------
// (broadcast pair loads + 16 scalar gathers in flight; R4 wide-load and R5
// readlane variants both regressed vs this structure). rowend[] replaces
// rowptr[n+1] for the gapped-bin CSR.
__global__ __launch_bounds__(256) void edge_agg_kernel(
    const float* __restrict__ xsrc,   // [Nsrc,64]
    const float* __restrict__ xdst,   // [Ndst,64]
    const int* __restrict__ rowptr,   // [Ndst]
    const int* __restrict__ rowend,   // [Ndst]
    const int2* __restrict__ pair,    // gapped, dst-sorted
    const float* __restrict__ lew,    // [64]
    const float* __restrict__ leb,    // [64]
    float* __restrict__ oa,           // [Ndst,64]  agg + xdst
    int N)
{
    int wave = threadIdx.x >> 6, lane = threadIdx.x & 63;
    int n = blockIdx.x * 4 + wave;
    if (n >= N) return;

    int start = __builtin_amdgcn_readfirstlane(rowptr[n]);
    int end   = __builtin_amdgcn_readfirstlane(rowend[n]);
    float lw = lew[lane], lb = leb[lane];
    float xd = xdst[(size_t)n * 64 + lane];   // independent: issue early

    float den = 0.0f, num = 0.0f;
    int j = start;

    if (j + 16 <= end) {
        int2 pb[16];
#pragma unroll
        for (int c = 0; c < 16; ++c) pb[c] = pair[j + c];

        for (; j + 32 <= end; j += 16) {
            float xv[16];
#pragma unroll
            for (int c = 0; c < 16; ++c) xv[c] = xsrc[pb[c].x * 64 + lane];
            int2 pn[16];
#pragma unroll
            for (int c = 0; c < 16; ++c) pn[c] = pair[j + 16 + c];
#pragma unroll
            for (int c = 0; c < 16; ++c) {
                float msg = relu_(fmaf(__int_as_float(pb[c].y), lw, xv[c] + lb)) + 1e-7f;
                float e = __expf(msg);
                den += e;
                num = fmaf(e, msg, num);
            }
#pragma unroll
            for (int c = 0; c < 16; ++c) pb[c] = pn[c];
        }
        {
            float xv[16];
#pragma unroll
            for (int c = 0; c < 16; ++c) xv[c] = xsrc[pb[c].x * 64 + lane];
#pragma unroll
            for (int c = 0; c < 16; ++c) {
                float msg = relu_(fmaf(__int_as_float(pb[c].y), lw, xv[c] + lb)) + 1e-7f;
                float e = __expf(msg);
                den += e;
                num = fmaf(e, msg, num);
            }
            j += 16;
        }
    }
    for (; j + 8 <= end; j += 8) {
        int2 p8[8];
#pragma unroll
        for (int c = 0; c < 8; ++c) p8[c] = pair[j + c];
        float xv[8];
#pragma unroll
        for (int c = 0; c < 8; ++c) xv[c] = xsrc[p8[c].x * 64 + lane];
#pragma unroll
        for (int c = 0; c < 8; ++c) {
            float msg = relu_(fmaf(__int_as_float(p8[c].y), lw, xv[c] + lb)) + 1e-7f;
            float e = __expf(msg);
            den += e;
            num = fmaf(e, msg, num);
        }
    }
    for (; j < end; ++j) {
        int2 p = pair[j];
        float xv = xsrc[p.x * 64 + lane];
        float msg = relu_(fmaf(__int_as_float(p.y), lw, xv + lb)) + 1e-7f;
        float e = __expf(msg);
        den += e;
        num = fmaf(e, msg, num);
    }

    oa[(size_t)n * 64 + lane] = num / (den + 1e-16f) + xd;
}

// ---------------- MLP + pred head: weights from L2; TN=16 for occupancy ----
// TN=40 -> 500 blocks was ~2 waves/SIMD (grid-starved, weight-load latency
// exposed). TN=16 -> 1250 blocks ~5 waves/SIMD; LDS ~14 KB.
__global__ __launch_bounds__(256, 4) void mlp_kernel(
    const float* __restrict__ oa,    // [N,64]
    float* __restrict__ feat,        // [N,64]
    const float* __restrict__ w1,    // [64,128]
    const float* __restrict__ b1,    // [128]
    const float* __restrict__ w2,    // [128,64]
    const float* __restrict__ b2,    // [64]
    const float* __restrict__ pw1,   // [64,64]
    const float* __restrict__ pb1,   // [64]
    const float* __restrict__ pw2,   // [64]
    const float* __restrict__ pb2,   // [1]
    float* __restrict__ outp,
    int N, int layer)
{
    __shared__ float act[TN][68];
    __shared__ float hid[TN][132];
    __shared__ float b1s[128];
    __shared__ float b2s[64];
    __shared__ float pb1s[64];
    __shared__ float pw2s[64];

    int tid = threadIdx.x;
    if (tid < 128) b1s[tid] = b1[tid];
    if (tid < 64) { b2s[tid] = b2[tid]; pb1s[tid] = pb1[tid]; pw2s[tid] = pw2[tid]; }
    float pb2v = pb2[0];

    int o4 = (tid & 31) * 4;
    int o2 = (tid & 31) * 2;
    int n2 = (tid >> 5) * 2;
    __syncthreads();

    int ntiles = N / TN;
    for (int tile = blockIdx.x; tile < ntiles; tile += gridDim.x) {
        int base = tile * TN;
        {
            // TN*16 = 256 float4s: one per thread
            const float4* g4 = (const float4*)(oa + (size_t)base * 64);
            *(float4*)&act[tid >> 4][(tid & 15) * 4] = g4[tid];
        }
        __syncthreads();

        {
            float acc[2][4];
#pragma unroll
            for (int i = 0; i < 2; ++i)
#pragma unroll
                for (int q = 0; q < 4; ++q) acc[i][q] = b1s[o4 + q];
#pragma unroll 2
            for (int k = 0; k < 64; k += 4) {
                float4 a[2];
#pragma unroll
                for (int i = 0; i < 2; ++i) a[i] = *(const float4*)&act[n2 + i][k];
                float4 w0 = *(const float4*)&w1[(k + 0) * 128 + o4];
                float4 wq1 = *(const float4*)&w1[(k + 1) * 128 + o4];
                float4 wq2 = *(const float4*)&w1[(k + 2) * 128 + o4];
                float4 wq3 = *(const float4*)&w1[(k + 3) * 128 + o4];
#pragma unroll
                for (int i = 0; i < 2; ++i) {
                    acc[i][0] = fmaf(a[i].x, w0.x, acc[i][0]);
                    acc[i][1] = fmaf(a[i].x, w0.y, acc[i][1]);
                    acc[i][2] = fmaf(a[i].x, w0.z, acc[i][2]);
                    acc[i][3] = fmaf(a[i].x, w0.w, acc[i][3]);
                    acc[i][0] = fmaf(a[i].y, wq1.x, acc[i][0]);
                    acc[i][1] = fmaf(a[i].y, wq1.y, acc[i][1]);
                    acc[i][2] = fmaf(a[i].y, wq1.z, acc[i][2]);
                    acc[i][3] = fmaf(a[i].y, wq1.w, acc[i][3]);
                    acc[i][0] = fmaf(a[i].z, wq2.x, acc[i][0]);
                    acc[i][1] = fmaf(a[i].z, wq2.y, acc[i][1]);
                    acc[i][2] = fmaf(a[i].z, wq2.z, acc[i][2]);
                    acc[i][3] = fmaf(a[i].z, wq2.w, acc[i][3]);
                    acc[i][0] = fmaf(a[i].w, wq3.x, acc[i][0]);
                    acc[i][1] = fmaf(a[i].w, wq3.y, acc[i][1]);
                    acc[i][2] = fmaf(a[i].w, wq3.z, acc[i][2]);
                    acc[i][3] = fmaf(a[i].w, wq3.w, acc[i][3]);
                }
            }
#pragma unroll
            for (int i = 0; i < 2; ++i) {
                float4 h4 = make_float4(relu_(acc[i][0]), relu_(acc[i][1]),
                                        relu_(acc[i][2]), relu_(acc[i][3]));
                *(float4*)&hid[n2 + i][o4] = h4;
            }
        }
        __syncthreads();

        {
            float acc[2][2];
#pragma unroll
            for (int i = 0; i < 2; ++i) { acc[i][0] = b2s[o2]; acc[i][1] = b2s[o2 + 1]; }
#pragma unroll 2
            for (int k = 0; k < 128; k += 4) {
                float4 a[2];
#pragma unroll
                for (int i = 0; i < 2; ++i) a[i] = *(const float4*)&hid[n2 + i][k];
                float2 w0 = *(const float2*)&w2[(k + 0) * 64 + o2];
                float2 wq1 = *(const float2*)&w2[(k + 1) * 64 + o2];
                float2 wq2 = *(const float2*)&w2[(k + 2) * 64 + o2];
                float2 wq3 = *(const float2*)&w2[(k + 3) * 64 + o2];
#pragma unroll
                for (int i = 0; i < 2; ++i) {
                    acc[i][0] = fmaf(a[i].x, w0.x, acc[i][0]);
                    acc[i][1] = fmaf(a[i].x, w0.y, acc[i][1]);
                    acc[i][0] = fmaf(a[i].y, wq1.x, acc[i][0]);
                    acc[i][1] = fmaf(a[i].y, wq1.y, acc[i][1]);
                    acc[i][0] = fmaf(a[i].z, wq2.x, acc[i][0]);
                    acc[i][1] = fmaf(a[i].z, wq2.y, acc[i][1]);
                    acc[i][0] = fmaf(a[i].w, wq3.x, acc[i][0]);
                    acc[i][1] = fmaf(a[i].w, wq3.y, acc[i][1]);
                }
            }
#pragma unroll
            for (int i = 0; i < 2; ++i) {
                float2 r2 = make_float2(acc[i][0], acc[i][1]);
                *(float2*)&feat[(size_t)(base + n2 + i) * 64 + o2] = r2;
                *(float2*)&act[n2 + i][o2] = r2;
            }
        }
        __syncthreads();

        {
            float acc[2][2];
#pragma unroll
            for (int i = 0; i < 2; ++i) { acc[i][0] = pb1s[o2]; acc[i][1] = pb1s[o2 + 1]; }
#pragma unroll 2
            for (int k = 0; k < 64; k += 4) {
                float4 a[2];
#pragma unroll
                for (int i = 0; i < 2; ++i) a[i] = *(const float4*)&act[n2 + i][k];
                float2 w0 = *(const float2*)&pw1[(k + 0) * 64 + o2];
                float2 wq1 = *(const float2*)&pw1[(k + 1) * 64 + o2];
                float2 wq2 = *(const float2*)&pw1[(k + 2) * 64 + o2];
                float2 wq3 = *(const float2*)&pw1[(k + 3) * 64 + o2];
#pragma unroll
                for (int i = 0; i < 2; ++i) {
                    acc[i][0] = fmaf(a[i].x, w0.x, acc[i][0]);
                    acc[i][1] = fmaf(a[i].x, w0.y, acc[i][1]);
                    acc[i][0] = fmaf(a[i].y, wq1.x, acc[i][0]);
                    acc[i][1] = fmaf(a[i].y, wq1.y, acc[i][1]);
                    acc[i][0] = fmaf(a[i].z, wq2.x, acc[i][0]);
                    acc[i][1] = fmaf(a[i].z, wq2.y, acc[i][1]);
                    acc[i][0] = fmaf(a[i].w, wq3.x, acc[i][0]);
                    acc[i][1] = fmaf(a[i].w, wq3.y, acc[i][1]);
                }
            }
            float pw2a = pw2s[o2], pw2b = pw2s[o2 + 1];
            float ps[2];
#pragma unroll
            for (int i = 0; i < 2; ++i)
                ps[i] = relu_(acc[i][0]) * pw2a + relu_(acc[i][1]) * pw2b;
#pragma unroll
            for (int msk = 16; msk >= 1; msk >>= 1) {
#pragma unroll
                for (int i = 0; i < 2; ++i)
                    ps[i] += __shfl_xor(ps[i], msk, 64);
            }
            if ((tid & 31) == 0) {
#pragma unroll
                for (int i = 0; i < 2; ++i)
                    outp[(size_t)(base + n2 + i) * NLAYER + layer] = ps[i] + pb2v;
            }
        }
        __syncthreads();
    }
}

extern "C" void kernel_launch(void* const* d_in, const int* in_sizes, int n_in,
                              void* d_out, int out_size, void* d_ws, size_t ws_size,
                              hipStream_t stream)
{
    const float* x_vals   = (const float*)d_in[0];
    const float* x_cons   = (const float*)d_in[1];
    const float* pe_vals  = (const float*)d_in[2];
    const float* pe_cons  = (const float*)d_in[3];
    const int*   ei_v2c   = (const int*)d_in[4];   // [2,E]
    const int*   ei_c2v   = (const int*)d_in[5];   // [2,E]
    const float* ew_v2c   = (const float*)d_in[6]; // [E,1]
    const float* ew_c2v   = (const float*)d_in[7];
    const float* enc_vals_w = (const float*)d_in[8];
    const float* enc_vals_b = (const float*)d_in[9];
    const float* pe_vals_w1 = (const float*)d_in[10];
    const float* pe_vals_b1 = (const float*)d_in[11];
    const float* pe_vals_w2 = (const float*)d_in[12];
    const float* pe_vals_b2 = (const float*)d_in[13];
    const float* enc_cons_w = (const float*)d_in[14];
    const float* enc_cons_b = (const float*)d_in[15];
    const float* pe_cons_w1 = (const float*)d_in[16];
    const float* pe_cons_b1 = (const float*)d_in[17];
    const float* pe_cons_w2 = (const float*)d_in[18];
    const float* pe_cons_b2 = (const float*)d_in[19];
    const float* v2c_edge_w = (const float*)d_in[20]; // [NL,1,64]
    const float* v2c_edge_b = (const float*)d_in[21]; // [NL,64]
    const float* v2c_w1     = (const float*)d_in[22]; // [NL,64,128]
    const float* v2c_b1     = (const float*)d_in[23]; // [NL,128]
    const float* v2c_w2     = (const float*)d_in[24]; // [NL,128,64]
    const float* v2c_b2     = (const float*)d_in[25]; // [NL,64]
    const float* c2v_edge_w = (const float*)d_in[26];
    const float* c2v_edge_b = (const float*)d_in[27];
    const float* c2v_w1     = (const float*)d_in[28];
    const float* c2v_b1     = (const float*)d_in[29];
    const float* c2v_w2     = (const float*)d_in[30];
    const float* c2v_b2     = (const float*)d_in[31];
    const float* pred_vals_w1 = (const float*)d_in[32];
    const float* pred_vals_b1 = (const float*)d_in[33];
    const float* pred_vals_w2 = (const float*)d_in[34];
    const float* pred_vals_b2 = (const float*)d_in[35];
    const float* pred_cons_w1 = (const float*)d_in[36];
    const float* pred_cons_b1 = (const float*)d_in[37];
    const float* pred_cons_w2 = (const float*)d_in[38];
    const float* pred_cons_b2 = (const float*)d_in[39];

    float* out = (float*)d_out;
    float* out_c = out + (size_t)NVN * NLAYER;

    const size_t NF = (size_t)NVN * 64;

    // Workspace layout (pair/stage are gapped: NB bins x CAP entries)
    float* ws     = (float*)d_ws;
    float* feat_v = ws;                 // NF
    float* feat_c = feat_v + NF;        // NF
    float* oa     = feat_c + NF;        // NF
    int2* v2c_pair  = (int2*)(oa + NF);        // NBCAP
    int2* c2v_pair  = v2c_pair + NBCAP;        // NBCAP
    int2* v2c_stage = c2v_pair + NBCAP;        // NBCAP
    int2* c2v_stage = v2c_stage + NBCAP;       // NBCAP
    int* ip = (int*)(c2v_stage + NBCAP);
    int* v2c_bincur  = ip; ip += NB;
    int* c2v_bincur  = ip; ip += NB;
    int* v2c_rowptr  = ip; ip += NCN;
    int* v2c_rowend  = ip; ip += NCN;
    int* c2v_rowptr  = ip; ip += NVN;
    int* c2v_rowend  = ip; ip += NVN;

    const int p1b = (NE + P1E - 1) / P1E;   // 245

    // CSR build (single-pass binning: no histogram/scan passes)
    bininit_kernel<<<1, 256, 0, stream>>>(v2c_bincur, c2v_bincur);
    scatter_p1_kernel<<<p1b, 256, 0, stream>>>(
        ei_v2c, ew_v2c, v2c_bincur, v2c_stage,
        ei_c2v, ew_c2v, c2v_bincur, c2v_stage);
    scatter_p2_kernel<<<2 * NB, 1024, 0, stream>>>(
        v2c_bincur, v2c_stage, v2c_rowptr, v2c_rowend, v2c_pair,
        c2v_bincur, c2v_stage, c2v_rowptr, c2v_rowend, c2v_pair);

    // Encoders
    encode2_kernel<<<(NVN + 3) / 4 + (NCN + 3) / 4, 256, 0, stream>>>(
        x_vals, pe_vals, enc_vals_w, enc_vals_b,
        pe_vals_w1, pe_vals_b1, pe_vals_w2, pe_vals_b2,
        x_cons, pe_cons, enc_cons_w, enc_cons_b,
        pe_cons_w1, pe_cons_b1, pe_cons_w2, pe_cons_b2,
        feat_v, feat_c);

    for (int i = 0; i < NLAYER; ++i) {
        // v2c: src = vals, dst = cons
        edge_agg_kernel<<<(NCN + 3) / 4, 256, 0, stream>>>(
            feat_v, feat_c, v2c_rowptr, v2c_rowend, v2c_pair,
            v2c_edge_w + (size_t)i * HID, v2c_edge_b + (size_t)i * HID,
            oa, NCN);
        mlp_kernel<<<NCN / TN, 256, 0, stream>>>(
            oa, feat_c,
            v2c_w1 + (size_t)i * 8192, v2c_b1 + (size_t)i * 128,
            v2c_w2 + (size_t)i * 8192, v2c_b2 + (size_t)i * 64,
            pred_cons_w1, pred_cons_b1, pred_cons_w2, pred_cons_b2,
            out_c, NCN, i);
        // c2v: src = cons (updated), dst = vals
        edge_agg_kernel<<<(NVN + 3) / 4, 256, 0, stream>>>(
            feat_c, feat_v, c2v_rowptr, c2v_rowend, c2v_pair,
            c2v_edge_w + (size_t)i * HID, c2v_edge_b + (size_t)i * HID,
            oa, NVN);
        mlp_kernel<<<NVN / TN, 256, 0, stream>>>(
            oa, feat_v,
            c2v_w1 + (size_t)i * 8192, c2v_b1 + (size_t)i * 128,
            c2v_w2 + (size_t)i * 8192, c2v_b2 + (size_t)i * 64,
            pred_vals_w1, pred_vals_b1, pred_vals_w2, pred_vals_b2,
            out, NVN, i);
    }
}

// Round 7
// 428.886 us; speedup vs baseline: 1.2414x; 1.2414x over previous
//
#include <hip/hip_runtime.h>

#define NVN 20000
#define NCN 20000
#define NE  500000
#define HID 64
#define NLAYER 3
#define TN 40      // nodes per MLP tile (proven R2 config)
#define BSH 8      // bin shift: 256 nodes/bin
#define NB 79      // ceil(20000/256) bins
#define CAPSH 14   // bin capacity 16384 (avg fill 6329, 2.6x margin)
#define CAP (1 << CAPSH)
#define NBCAP (NB * CAP)
#define P1E 2048   // edges per scatter block -> 245 blocks

__device__ __forceinline__ float relu_(float x) { return fmaxf(x, 0.0f); }

// ---------------- bincur init: bin b allocates from b*CAP ------------------
__global__ __launch_bounds__(256) void bininit_kernel(
    int* __restrict__ bincurA, int* __restrict__ bincurB)
{
    int t = threadIdx.x;
    if (t < NB) { bincurA[t] = t << CAPSH; bincurB[t] = t << CAPSH; }
}

// ---------------- Binned scatter pass 1: edges -> bin-staged ----------------
// stage element: (src | dst<<16, bitcast(w)); both < 2^16. Bins are
// fixed-capacity (CAP) segments; blocks allocate via atomicAdd on bincur.
__global__ __launch_bounds__(256) void scatter_p1_kernel(
    const int* __restrict__ eiA, const float* __restrict__ ewA,
    int* __restrict__ bincurA, int2* __restrict__ stageA,
    const int* __restrict__ eiB, const float* __restrict__ ewB,
    int* __restrict__ bincurB, int2* __restrict__ stageB)
{
    __shared__ int rnk[P1E];            // 8 KB
    __shared__ int cnt[NB], base_[NB];
    int t = threadIdx.x;
    int e0 = blockIdx.x * P1E;

    for (int g = 0; g < 2; ++g) {
        const int* ei   = g ? eiB : eiA;
        const float* ew = g ? ewB : ewA;
        int* bincur     = g ? bincurB : bincurA;
        int2* stage     = g ? stageB : stageA;

        if (t < NB) cnt[t] = 0;
        __syncthreads();
        for (int i = t; i < P1E; i += 256) {
            int e = e0 + i;
            if (e < NE) {
                int d = ei[NE + e];
                rnk[i] = atomicAdd(&cnt[d >> BSH], 1);
            }
        }
        __syncthreads();
        if (t < NB && cnt[t] > 0) base_[t] = atomicAdd(&bincur[t], cnt[t]);
        __syncthreads();
        for (int i = t; i < P1E; i += 256) {
            int e = e0 + i;
            if (e < NE) {
                int s = ei[e], d = ei[NE + e];
                float w = ew[e];
                stage[base_[d >> BSH] + rnk[i]] =
                    make_int2((int)((unsigned)s | ((unsigned)d << 16)), __float_as_int(w));
            }
        }
        __syncthreads();
    }
}

// ---------------- Pass 2: LDS counting sort per bin ------------------------
// one block per (graph, bin); bin b occupies [b*CAP, bincur[b]) in stage.
// pair[] keeps the gapped layout (per-node ranges contiguous; inter-bin gaps
// never dereferenced). rowend[] replaces rowptr[n+1].
__global__ __launch_bounds__(1024) void scatter_p2_kernel(
    const int* __restrict__ bincurA, const int2* __restrict__ stageA,
    int* __restrict__ rowptrA, int* __restrict__ rowendA, int2* __restrict__ pairA,
    const int* __restrict__ bincurB, const int2* __restrict__ stageB,
    int* __restrict__ rowptrB, int* __restrict__ rowendB, int2* __restrict__ pairB)
{
    __shared__ int deg[256], pfx[256], cur[256];
    int g = blockIdx.x / NB;
    int b = blockIdx.x % NB;
    const int* bincur  = g ? bincurB : bincurA;
    const int2* stage  = g ? stageB : stageA;
    int* rowptr        = g ? rowptrB : rowptrA;
    int* rowend        = g ? rowendB : rowendA;
    int2* pair         = g ? pairB : pairA;

    int d0 = b << BSH;
    int d1 = min(d0 + 256, NCN);   // NVN == NCN
    int nd = d1 - d0;
    int t = threadIdx.x;
    int estart = b << CAPSH;
    int eend = bincur[b];

    if (t < 256) deg[t] = 0;
    __syncthreads();
    for (int e = estart + t; e < eend; e += 1024) {
        int dst = (int)((unsigned)stage[e].x >> 16);
        atomicAdd(&deg[dst - d0], 1);
    }
    __syncthreads();
    if (t < 256) pfx[t] = deg[t];
    __syncthreads();
    for (int off = 1; off < 256; off <<= 1) {
        int v = (t >= off && t < 256) ? pfx[t - off] : 0;
        __syncthreads();
        if (t < 256) pfx[t] += v;
        __syncthreads();
    }
    if (t < nd) {
        int ex = estart + pfx[t] - deg[t];   // exclusive
        rowptr[d0 + t] = ex;
        rowend[d0 + t] = estart + pfx[t];
        cur[t] = ex;
    }
    __syncthreads();
    for (int e = estart + t; e < eend; e += 1024) {
        int2 s = stage[e];
        unsigned u = (unsigned)s.x;
        int src = (int)(u & 0xFFFFu);
        int dst = (int)(u >> 16);
        int p = atomicAdd(&cur[dst - d0], 1);
        pair[p] = make_int2(src, s.y);
    }
}

// ---------------- Encoders (both node sets in one dispatch) ----------------
__global__ __launch_bounds__(256) void encode2_kernel(
    const float* __restrict__ xv, const float* __restrict__ pev,
    const float* __restrict__ ewv, const float* __restrict__ ebv,
    const float* __restrict__ pw1v, const float* __restrict__ pb1v,
    const float* __restrict__ pw2v, const float* __restrict__ pb2v,
    const float* __restrict__ xc, const float* __restrict__ pec,
    const float* __restrict__ ewc, const float* __restrict__ ebc,
    const float* __restrict__ pw1c, const float* __restrict__ pb1c,
    const float* __restrict__ pw2c, const float* __restrict__ pb2c,
    float* __restrict__ outv, float* __restrict__ outc)
{
    __shared__ float sh[4][64];
    const int VB = (NVN + 3) / 4;
    int wave = threadIdx.x >> 6, lane = threadIdx.x & 63;
    int b = blockIdx.x;
    bool isC = (b >= VB);
    const float* x   = isC ? xc : xv;
    const float* pe  = isC ? pec : pev;
    const float* ew  = isC ? ewc : ewv;
    const float* eb  = isC ? ebc : ebv;
    const float* pw1 = isC ? pw1c : pw1v;
    const float* pb1 = isC ? pb1c : pb1v;
    const float* pw2 = isC ? pw2c : pw2v;
    const float* pb2 = isC ? pb2c : pb2v;
    float* out = isC ? outc : outv;
    int N = isC ? NCN : NVN;
    int n = (isC ? b - VB : b) * 4 + wave;
    if (n >= N) return;

    float accp = pb1[lane], accm = accp;
#pragma unroll
    for (int k = 0; k < 8; ++k) {
        float p = pe[n * 8 + k];
        float w = pw1[k * 64 + lane];
        accp += p * w;
        accm -= p * w;
    }
    float hs = 0.5f * (relu_(accp) + relu_(accm));
    float* my = sh[wave];
    my[lane] = hs;
    __builtin_amdgcn_wave_barrier();

    int col = lane & 31;
    float peo = pb2[col];
#pragma unroll
    for (int k = 0; k < 64; k += 4) {
        float4 hv = *(const float4*)(my + k);
        peo = fmaf(hv.x, pw2[(k + 0) * 32 + col], peo);
        peo = fmaf(hv.y, pw2[(k + 1) * 32 + col], peo);
        peo = fmaf(hv.z, pw2[(k + 2) * 32 + col], peo);
        peo = fmaf(hv.w, pw2[(k + 3) * 32 + col], peo);
    }
    float lino = x[n * 2 + 0] * ew[col] + x[n * 2 + 1] * ew[32 + col] + eb[col];
    float h = (lane < 32) ? lino : peo;
    out[n * 64 + lane] = relu_(h);
}

// ---------------- Edge aggregation: 8-deep pipeline, 8 waves/SIMD ----------
// R2's 16-deep used ~105 VGPR -> 4 waves/SIMD. 8-deep fits <=64 VGPR
// (enforced by launch_bounds(256,8)) -> 8 waves/SIMD: same outstanding
// gathers per SIMD (8x8 = 16x4) but 2x wave-level latency tolerance and a
// shorter tail. No-max softmax as validated since round 1.
__global__ __launch_bounds__(256, 8) void edge_agg_kernel(
    const float* __restrict__ xsrc,   // [Nsrc,64]
    const float* __restrict__ xdst,   // [Ndst,64]
    const int* __restrict__ rowptr,   // [Ndst]
    const int* __restrict__ rowend,   // [Ndst]
    const int2* __restrict__ pair,    // gapped, dst-sorted
    const float* __restrict__ lew,    // [64]
    const float* __restrict__ leb,    // [64]
    float* __restrict__ oa,           // [Ndst,64]  agg + xdst
    int N)
{
    int wave = threadIdx.x >> 6, lane = threadIdx.x & 63;
    int n = blockIdx.x * 4 + wave;
    if (n >= N) return;

    int start = __builtin_amdgcn_readfirstlane(rowptr[n]);
    int end   = __builtin_amdgcn_readfirstlane(rowend[n]);
    float lw = lew[lane], lb = leb[lane];
    float xd = xdst[(size_t)n * 64 + lane];   // independent: issue early

    float den = 0.0f, num = 0.0f;
    int j = start;

    if (j + 8 <= end) {
        int2 pb[8];
#pragma unroll
        for (int c = 0; c < 8; ++c) pb[c] = pair[j + c];

        for (; j + 16 <= end; j += 8) {
            float xv[8];
#pragma unroll
            for (int c = 0; c < 8; ++c) xv[c] = xsrc[pb[c].x * 64 + lane];
            int2 pn[8];
#pragma unroll
            for (int c = 0; c < 8; ++c) pn[c] = pair[j + 8 + c];
#pragma unroll
            for (int c = 0; c < 8; ++c) {
                float msg = relu_(fmaf(__int_as_float(pb[c].y), lw, xv[c] + lb)) + 1e-7f;
                float e = __expf(msg);
                den += e;
                num = fmaf(e, msg, num);
            }
#pragma unroll
            for (int c = 0; c < 8; ++c) pb[c] = pn[c];
        }
        {   // last full 8 (pairs already in registers)
            float xv[8];
#pragma unroll
            for (int c = 0; c < 8; ++c) xv[c] = xsrc[pb[c].x * 64 + lane];
#pragma unroll
            for (int c = 0; c < 8; ++c) {
                float msg = relu_(fmaf(__int_as_float(pb[c].y), lw, xv[c] + lb)) + 1e-7f;
                float e = __expf(msg);
                den += e;
                num = fmaf(e, msg, num);
            }
            j += 8;
        }
    }
    for (; j < end; ++j) {
        int2 p = pair[j];
        float xv = xsrc[p.x * 64 + lane];
        float msg = relu_(fmaf(__int_as_float(p.y), lw, xv + lb)) + 1e-7f;
        float e = __expf(msg);
        den += e;
        num = fmaf(e, msg, num);
    }

    oa[(size_t)n * 64 + lane] = num / (den + 1e-16f) + xd;
}

// ---------------- MLP + pred head: weights from global (L2-broadcast) ------
// Proven R2 config: TN=40, grid 500, 4 blocks/CU.
__global__ __launch_bounds__(256, 4) void mlp_kernel(
    const float* __restrict__ oa,    // [N,64]
    float* __restrict__ feat,        // [N,64]
    const float* __restrict__ w1,    // [64,128]
    const float* __restrict__ b1,    // [128]
    const float* __restrict__ w2,    // [128,64]
    const float* __restrict__ b2,    // [64]
    const float* __restrict__ pw1,   // [64,64]
    const float* __restrict__ pb1,   // [64]
    const float* __restrict__ pw2,   // [64]
    const float* __restrict__ pb2,   // [1]
    float* __restrict__ outp,
    int N, int layer)
{
    __shared__ float act[TN][68];
    __shared__ float hid[TN][132];
    __shared__ float b1s[128];
    __shared__ float b2s[64];
    __shared__ float pb1s[64];
    __shared__ float pw2s[64];

    int tid = threadIdx.x;
    if (tid < 128) b1s[tid] = b1[tid];
    if (tid < 64) { b2s[tid] = b2[tid]; pb1s[tid] = pb1[tid]; pw2s[tid] = pw2[tid]; }
    float pb2v = pb2[0];

    int o4 = (tid & 31) * 4;
    int o2 = (tid & 31) * 2;
    int n5 = (tid >> 5) * 5;
    __syncthreads();

    int ntiles = N / TN;
    for (int tile = blockIdx.x; tile < ntiles; tile += gridDim.x) {
        int base = tile * TN;
        {
            const float4* g4 = (const float4*)(oa + (size_t)base * 64);
            for (int i = tid; i < TN * 16; i += 256)
                *(float4*)&act[i >> 4][(i & 15) * 4] = g4[i];
        }
        __syncthreads();

        {
            float acc[5][4];
#pragma unroll
            for (int i = 0; i < 5; ++i)
#pragma unroll
                for (int q = 0; q < 4; ++q) acc[i][q] = b1s[o4 + q];
#pragma unroll 2
            for (int k = 0; k < 64; k += 4) {
                float4 a[5];
#pragma unroll
                for (int i = 0; i < 5; ++i) a[i] = *(const float4*)&act[n5 + i][k];
                float4 w0 = *(const float4*)&w1[(k + 0) * 128 + o4];
                float4 wq1 = *(const float4*)&w1[(k + 1) * 128 + o4];
                float4 wq2 = *(const float4*)&w1[(k + 2) * 128 + o4];
                float4 wq3 = *(const float4*)&w1[(k + 3) * 128 + o4];
#pragma unroll
                for (int i = 0; i < 5; ++i) {
                    acc[i][0] = fmaf(a[i].x, w0.x, acc[i][0]);
                    acc[i][1] = fmaf(a[i].x, w0.y, acc[i][1]);
                    acc[i][2] = fmaf(a[i].x, w0.z, acc[i][2]);
                    acc[i][3] = fmaf(a[i].x, w0.w, acc[i][3]);
                    acc[i][0] = fmaf(a[i].y, wq1.x, acc[i][0]);
                    acc[i][1] = fmaf(a[i].y, wq1.y, acc[i][1]);
                    acc[i][2] = fmaf(a[i].y, wq1.z, acc[i][2]);
                    acc[i][3] = fmaf(a[i].y, wq1.w, acc[i][3]);
                    acc[i][0] = fmaf(a[i].z, wq2.x, acc[i][0]);
                    acc[i][1] = fmaf(a[i].z, wq2.y, acc[i][1]);
                    acc[i][2] = fmaf(a[i].z, wq2.z, acc[i][2]);
                    acc[i][3] = fmaf(a[i].z, wq2.w, acc[i][3]);
                    acc[i][0] = fmaf(a[i].w, wq3.x, acc[i][0]);
                    acc[i][1] = fmaf(a[i].w, wq3.y, acc[i][1]);
                    acc[i][2] = fmaf(a[i].w, wq3.z, acc[i][2]);
                    acc[i][3] = fmaf(a[i].w, wq3.w, acc[i][3]);
                }
            }
#pragma unroll
            for (int i = 0; i < 5; ++i) {
                float4 h4 = make_float4(relu_(acc[i][0]), relu_(acc[i][1]),
                                        relu_(acc[i][2]), relu_(acc[i][3]));
                *(float4*)&hid[n5 + i][o4] = h4;
            }
        }
        __syncthreads();

        {
            float acc[5][2];
#pragma unroll
            for (int i = 0; i < 5; ++i) { acc[i][0] = b2s[o2]; acc[i][1] = b2s[o2 + 1]; }
#pragma unroll 2
            for (int k = 0; k < 128; k += 4) {
                float4 a[5];
#pragma unroll
                for (int i = 0; i < 5; ++i) a[i] = *(const float4*)&hid[n5 + i][k];
                float2 w0 = *(const float2*)&w2[(k + 0) * 64 + o2];
                float2 wq1 = *(const float2*)&w2[(k + 1) * 64 + o2];
                float2 wq2 = *(const float2*)&w2[(k + 2) * 64 + o2];
                float2 wq3 = *(const float2*)&w2[(k + 3) * 64 + o2];
#pragma unroll
                for (int i = 0; i < 5; ++i) {
                    acc[i][0] = fmaf(a[i].x, w0.x, acc[i][0]);
                    acc[i][1] = fmaf(a[i].x, w0.y, acc[i][1]);
                    acc[i][0] = fmaf(a[i].y, wq1.x, acc[i][0]);
                    acc[i][1] = fmaf(a[i].y, wq1.y, acc[i][1]);
                    acc[i][0] = fmaf(a[i].z, wq2.x, acc[i][0]);
                    acc[i][1] = fmaf(a[i].z, wq2.y, acc[i][1]);
                    acc[i][0] = fmaf(a[i].w, wq3.x, acc[i][0]);
                    acc[i][1] = fmaf(a[i].w, wq3.y, acc[i][1]);
                }
            }
#pragma unroll
            for (int i = 0; i < 5; ++i) {
                float2 r2 = make_float2(acc[i][0], acc[i][1]);
                *(float2*)&feat[(size_t)(base + n5 + i) * 64 + o2] = r2;
                *(float2*)&act[n5 + i][o2] = r2;
            }
        }
        __syncthreads();

        {
            float acc[5][2];
#pragma unroll
            for (int i = 0; i < 5; ++i) { acc[i][0] = pb1s[o2]; acc[i][1] = pb1s[o2 + 1]; }
#pragma unroll 2
            for (int k = 0; k < 64; k += 4) {
                float4 a[5];
#pragma unroll
                for (int i = 0; i < 5; ++i) a[i] = *(const float4*)&act[n5 + i][k];
                float2 w0 = *(const float2*)&pw1[(k + 0) * 64 + o2];
                float2 wq1 = *(const float2*)&pw1[(k + 1) * 64 + o2];
                float2 wq2 = *(const float2*)&pw1[(k + 2) * 64 + o2];
                float2 wq3 = *(const float2*)&pw1[(k + 3) * 64 + o2];
#pragma unroll
                for (int i = 0; i < 5; ++i) {
                    acc[i][0] = fmaf(a[i].x, w0.x, acc[i][0]);
                    acc[i][1] = fmaf(a[i].x, w0.y, acc[i][1]);
                    acc[i][0] = fmaf(a[i].y, wq1.x, acc[i][0]);
                    acc[i][1] = fmaf(a[i].y, wq1.y, acc[i][1]);
                    acc[i][0] = fmaf(a[i].z, wq2.x, acc[i][0]);
                    acc[i][1] = fmaf(a[i].z, wq2.y, acc[i][1]);
                    acc[i][0] = fmaf(a[i].w, wq3.x, acc[i][0]);
                    acc[i][1] = fmaf(a[i].w, wq3.y, acc[i][1]);
                }
            }
            float pw2a = pw2s[o2], pw2b = pw2s[o2 + 1];
            float ps[5];
#pragma unroll
            for (int i = 0; i < 5; ++i)
                ps[i] = relu_(acc[i][0]) * pw2a + relu_(acc[i][1]) * pw2b;
#pragma unroll
            for (int msk = 16; msk >= 1; msk >>= 1) {
#pragma unroll
                for (int i = 0; i < 5; ++i)
                    ps[i] += __shfl_xor(ps[i], msk, 64);
            }
            if ((tid & 31) == 0) {
#pragma unroll
                for (int i = 0; i < 5; ++i)
                    outp[(size_t)(base + n5 + i) * NLAYER + layer] = ps[i] + pb2v;
            }
        }
        __syncthreads();
    }
}

extern "C" void kernel_launch(void* const* d_in, const int* in_sizes, int n_in,
                              void* d_out, int out_size, void* d_ws, size_t ws_size,
                              hipStream_t stream)
{
    const float* x_vals   = (const float*)d_in[0];
    const float* x_cons   = (const float*)d_in[1];
    const float* pe_vals  = (const float*)d_in[2];
    const float* pe_cons  = (const float*)d_in[3];
    const int*   ei_v2c   = (const int*)d_in[4];   // [2,E]
    const int*   ei_c2v   = (const int*)d_in[5];   // [2,E]
    const float* ew_v2c   = (const float*)d_in[6]; // [E,1]
    const float* ew_c2v   = (const float*)d_in[7];
    const float* enc_vals_w = (const float*)d_in[8];
    const float* enc_vals_b = (const float*)d_in[9];
    const float* pe_vals_w1 = (const float*)d_in[10];
    const float* pe_vals_b1 = (const float*)d_in[11];
    const float* pe_vals_w2 = (const float*)d_in[12];
    const float* pe_vals_b2 = (const float*)d_in[13];
    const float* enc_cons_w = (const float*)d_in[14];
    const float* enc_cons_b = (const float*)d_in[15];
    const float* pe_cons_w1 = (const float*)d_in[16];
    const float* pe_cons_b1 = (const float*)d_in[17];
    const float* pe_cons_w2 = (const float*)d_in[18];
    const float* pe_cons_b2 = (const float*)d_in[19];
    const float* v2c_edge_w = (const float*)d_in[20]; // [NL,1,64]
    const float* v2c_edge_b = (const float*)d_in[21]; // [NL,64]
    const float* v2c_w1     = (const float*)d_in[22]; // [NL,64,128]
    const float* v2c_b1     = (const float*)d_in[23]; // [NL,128]
    const float* v2c_w2     = (const float*)d_in[24]; // [NL,128,64]
    const float* v2c_b2     = (const float*)d_in[25]; // [NL,64]
    const float* c2v_edge_w = (const float*)d_in[26];
    const float* c2v_edge_b = (const float*)d_in[27];
    const float* c2v_w1     = (const float*)d_in[28];
    const float* c2v_b1     = (const float*)d_in[29];
    const float* c2v_w2     = (const float*)d_in[30];
    const float* c2v_b2     = (const float*)d_in[31];
    const float* pred_vals_w1 = (const float*)d_in[32];
    const float* pred_vals_b1 = (const float*)d_in[33];
    const float* pred_vals_w2 = (const float*)d_in[34];
    const float* pred_vals_b2 = (const float*)d_in[35];
    const float* pred_cons_w1 = (const float*)d_in[36];
    const float* pred_cons_b1 = (const float*)d_in[37];
    const float* pred_cons_w2 = (const float*)d_in[38];
    const float* pred_cons_b2 = (const float*)d_in[39];

    float* out = (float*)d_out;
    float* out_c = out + (size_t)NVN * NLAYER;

    const size_t NF = (size_t)NVN * 64;

    // Workspace layout (pair/stage are gapped: NB bins x CAP entries)
    float* ws     = (float*)d_ws;
    float* feat_v = ws;                 // NF
    float* feat_c = feat_v + NF;        // NF
    float* oa     = feat_c + NF;        // NF
    int2* v2c_pair  = (int2*)(oa + NF);        // NBCAP
    int2* c2v_pair  = v2c_pair + NBCAP;        // NBCAP
    int2* v2c_stage = c2v_pair + NBCAP;        // NBCAP
    int2* c2v_stage = v2c_stage + NBCAP;       // NBCAP
    int* ip = (int*)(c2v_stage + NBCAP);
    int* v2c_bincur  = ip; ip += NB;
    int* c2v_bincur  = ip; ip += NB;
    int* v2c_rowptr  = ip; ip += NCN;
    int* v2c_rowend  = ip; ip += NCN;
    int* c2v_rowptr  = ip; ip += NVN;
    int* c2v_rowend  = ip; ip += NVN;

    const int p1b = (NE + P1E - 1) / P1E;   // 245

    // CSR build (single-pass binning: no histogram/scan passes)
    bininit_kernel<<<1, 256, 0, stream>>>(v2c_bincur, c2v_bincur);
    scatter_p1_kernel<<<p1b, 256, 0, stream>>>(
        ei_v2c, ew_v2c, v2c_bincur, v2c_stage,
        ei_c2v, ew_c2v, c2v_bincur, c2v_stage);
    scatter_p2_kernel<<<2 * NB, 1024, 0, stream>>>(
        v2c_bincur, v2c_stage, v2c_rowptr, v2c_rowend, v2c_pair,
        c2v_bincur, c2v_stage, c2v_rowptr, c2v_rowend, c2v_pair);

    // Encoders
    encode2_kernel<<<(NVN + 3) / 4 + (NCN + 3) / 4, 256, 0, stream>>>(
        x_vals, pe_vals, enc_vals_w, enc_vals_b,
        pe_vals_w1, pe_vals_b1, pe_vals_w2, pe_vals_b2,
        x_cons, pe_cons, enc_cons_w, enc_cons_b,
        pe_cons_w1, pe_cons_b1, pe_cons_w2, pe_cons_b2,
        feat_v, feat_c);

    for (int i = 0; i < NLAYER; ++i) {
        // v2c: src = vals, dst = cons
        edge_agg_kernel<<<(NCN + 3) / 4, 256, 0, stream>>>(
            feat_v, feat_c, v2c_rowptr, v2c_rowend, v2c_pair,
            v2c_edge_w + (size_t)i * HID, v2c_edge_b + (size_t)i * HID,
            oa, NCN);
        mlp_kernel<<<NCN / TN, 256, 0, stream>>>(
            oa, feat_c,
            v2c_w1 + (size_t)i * 8192, v2c_b1 + (size_t)i * 128,
            v2c_w2 + (size_t)i * 8192, v2c_b2 + (size_t)i * 64,
            pred_cons_w1, pred_cons_b1, pred_cons_w2, pred_cons_b2,
            out_c, NCN, i);
        // c2v: src = cons (updated), dst = vals
        edge_agg_kernel<<<(NVN + 3) / 4, 256, 0, stream>>>(
            feat_c, feat_v, c2v_rowptr, c2v_rowend, c2v_pair,
            c2v_edge_w + (size_t)i * HID, c2v_edge_b + (size_t)i * HID,
            oa, NVN);
        mlp_kernel<<<NVN / TN, 256, 0, stream>>>(
            oa, feat_v,
            c2v_w1 + (size_t)i * 8192, c2v_b1 + (size_t)i * 128,
            c2v_w2 + (size_t)i * 8192, c2v_b2 + (size_t)i * 64,
            pred_vals_w1, pred_vals_b1, pred_vals_w2, pred_vals_b2,
            out, NVN, i);
    }
}

// Round 8
// 426.040 us; speedup vs baseline: 1.2497x; 1.0067x over previous
//
#include <hip/hip_runtime.h>
#include <hip/hip_fp16.h>

#define NVN 20000
#define NCN 20000
#define NE  500000
#define HID 64
#define NLAYER 3
#define TN 40      // nodes per MLP tile (proven R2 config)
#define BSH 8      // bin shift: 256 nodes/bin
#define NB 79      // ceil(20000/256) bins
#define CAPSH 14   // bin capacity 16384 (avg fill 6329, 2.6x margin)
#define CAP (1 << CAPSH)
#define NBCAP (NB * CAP)
#define P1E 2048   // edges per scatter block -> 245 blocks

__device__ __forceinline__ float relu_(float x) { return fmaxf(x, 0.0f); }

// ---------------- bincur init: bin b allocates from b*CAP ------------------
__global__ __launch_bounds__(256) void bininit_kernel(
    int* __restrict__ bincurA, int* __restrict__ bincurB)
{
    int t = threadIdx.x;
    if (t < NB) { bincurA[t] = t << CAPSH; bincurB[t] = t << CAPSH; }
}

// ---------------- Binned scatter pass 1: edges -> bin-staged ----------------
// stage element: (src | dst<<16, bitcast(w)); both < 2^16. Bins are
// fixed-capacity (CAP) segments; blocks allocate via atomicAdd on bincur.
__global__ __launch_bounds__(256) void scatter_p1_kernel(
    const int* __restrict__ eiA, const float* __restrict__ ewA,
    int* __restrict__ bincurA, int2* __restrict__ stageA,
    const int* __restrict__ eiB, const float* __restrict__ ewB,
    int* __restrict__ bincurB, int2* __restrict__ stageB)
{
    __shared__ int rnk[P1E];            // 8 KB
    __shared__ int cnt[NB], base_[NB];
    int t = threadIdx.x;
    int e0 = blockIdx.x * P1E;

    for (int g = 0; g < 2; ++g) {
        const int* ei   = g ? eiB : eiA;
        const float* ew = g ? ewB : ewA;
        int* bincur     = g ? bincurB : bincurA;
        int2* stage     = g ? stageB : stageA;

        if (t < NB) cnt[t] = 0;
        __syncthreads();
        for (int i = t; i < P1E; i += 256) {
            int e = e0 + i;
            if (e < NE) {
                int d = ei[NE + e];
                rnk[i] = atomicAdd(&cnt[d >> BSH], 1);
            }
        }
        __syncthreads();
        if (t < NB && cnt[t] > 0) base_[t] = atomicAdd(&bincur[t], cnt[t]);
        __syncthreads();
        for (int i = t; i < P1E; i += 256) {
            int e = e0 + i;
            if (e < NE) {
                int s = ei[e], d = ei[NE + e];
                float w = ew[e];
                stage[base_[d >> BSH] + rnk[i]] =
                    make_int2((int)((unsigned)s | ((unsigned)d << 16)), __float_as_int(w));
            }
        }
        __syncthreads();
    }
}

// ---------------- Pass 2: LDS counting sort per bin ------------------------
// one block per (graph, bin); bin b occupies [b*CAP, bincur[b]) in stage.
// pair[] keeps the gapped layout (per-node ranges contiguous; inter-bin gaps
// never dereferenced). rowend[] replaces rowptr[n+1].
__global__ __launch_bounds__(1024) void scatter_p2_kernel(
    const int* __restrict__ bincurA, const int2* __restrict__ stageA,
    int* __restrict__ rowptrA, int* __restrict__ rowendA, int2* __restrict__ pairA,
    const int* __restrict__ bincurB, const int2* __restrict__ stageB,
    int* __restrict__ rowptrB, int* __restrict__ rowendB, int2* __restrict__ pairB)
{
    __shared__ int deg[256], pfx[256], cur[256];
    int g = blockIdx.x / NB;
    int b = blockIdx.x % NB;
    const int* bincur  = g ? bincurB : bincurA;
    const int2* stage  = g ? stageB : stageA;
    int* rowptr        = g ? rowptrB : rowptrA;
    int* rowend        = g ? rowendB : rowendA;
    int2* pair         = g ? pairB : pairA;

    int d0 = b << BSH;
    int d1 = min(d0 + 256, NCN);   // NVN == NCN
    int nd = d1 - d0;
    int t = threadIdx.x;
    int estart = b << CAPSH;
    int eend = bincur[b];

    if (t < 256) deg[t] = 0;
    __syncthreads();
    for (int e = estart + t; e < eend; e += 1024) {
        int dst = (int)((unsigned)stage[e].x >> 16);
        atomicAdd(&deg[dst - d0], 1);
    }
    __syncthreads();
    if (t < 256) pfx[t] = deg[t];
    __syncthreads();
    for (int off = 1; off < 256; off <<= 1) {
        int v = (t >= off && t < 256) ? pfx[t - off] : 0;
        __syncthreads();
        if (t < 256) pfx[t] += v;
        __syncthreads();
    }
    if (t < nd) {
        int ex = estart + pfx[t] - deg[t];   // exclusive
        rowptr[d0 + t] = ex;
        rowend[d0 + t] = estart + pfx[t];
        cur[t] = ex;
    }
    __syncthreads();
    for (int e = estart + t; e < eend; e += 1024) {
        int2 s = stage[e];
        unsigned u = (unsigned)s.x;
        int src = (int)(u & 0xFFFFu);
        int dst = (int)(u >> 16);
        int p = atomicAdd(&cur[dst - d0], 1);
        pair[p] = make_int2(src, s.y);
    }
}

// ---------------- Encoders (both node sets; fp32 + fp16 mirror out) --------
__global__ __launch_bounds__(256) void encode2_kernel(
    const float* __restrict__ xv, const float* __restrict__ pev,
    const float* __restrict__ ewv, const float* __restrict__ ebv,
    const float* __restrict__ pw1v, const float* __restrict__ pb1v,
    const float* __restrict__ pw2v, const float* __restrict__ pb2v,
    const float* __restrict__ xc, const float* __restrict__ pec,
    const float* __restrict__ ewc, const float* __restrict__ ebc,
    const float* __restrict__ pw1c, const float* __restrict__ pb1c,
    const float* __restrict__ pw2c, const float* __restrict__ pb2c,
    float* __restrict__ outv, float* __restrict__ outc,
    __half* __restrict__ outv16, __half* __restrict__ outc16)
{
    __shared__ float sh[4][64];
    const int VB = (NVN + 3) / 4;
    int wave = threadIdx.x >> 6, lane = threadIdx.x & 63;
    int b = blockIdx.x;
    bool isC = (b >= VB);
    const float* x   = isC ? xc : xv;
    const float* pe  = isC ? pec : pev;
    const float* ew  = isC ? ewc : ewv;
    const float* eb  = isC ? ebc : ebv;
    const float* pw1 = isC ? pw1c : pw1v;
    const float* pb1 = isC ? pb1c : pb1v;
    const float* pw2 = isC ? pw2c : pw2v;
    const float* pb2 = isC ? pb2c : pb2v;
    float* out = isC ? outc : outv;
    __half* out16 = isC ? outc16 : outv16;
    int N = isC ? NCN : NVN;
    int n = (isC ? b - VB : b) * 4 + wave;
    if (n >= N) return;

    float accp = pb1[lane], accm = accp;
#pragma unroll
    for (int k = 0; k < 8; ++k) {
        float p = pe[n * 8 + k];
        float w = pw1[k * 64 + lane];
        accp += p * w;
        accm -= p * w;
    }
    float hs = 0.5f * (relu_(accp) + relu_(accm));
    float* my = sh[wave];
    my[lane] = hs;
    __builtin_amdgcn_wave_barrier();

    int col = lane & 31;
    float peo = pb2[col];
#pragma unroll
    for (int k = 0; k < 64; k += 4) {
        float4 hv = *(const float4*)(my + k);
        peo = fmaf(hv.x, pw2[(k + 0) * 32 + col], peo);
        peo = fmaf(hv.y, pw2[(k + 1) * 32 + col], peo);
        peo = fmaf(hv.z, pw2[(k + 2) * 32 + col], peo);
        peo = fmaf(hv.w, pw2[(k + 3) * 32 + col], peo);
    }
    float lino = x[n * 2 + 0] * ew[col] + x[n * 2 + 1] * ew[32 + col] + eb[col];
    float h = (lane < 32) ? lino : peo;
    float r = relu_(h);
    out[n * 64 + lane] = r;
    out16[n * 64 + lane] = __float2half(r);
}

// ---------------- Edge aggregation: 8-deep pipeline, fp16 gathers ----------
// R7 evidence: doubling TLP moved edge_agg only ~4% -> throughput-bound on
// gather bytes (128 MB/dispatch fp32 = ~5.1 TB/s effective). fp16 mirror
// halves gather traffic; residual xd and oa stay fp32. No-max softmax as
// validated since round 1.
__global__ __launch_bounds__(256, 8) void edge_agg_kernel(
    const __half* __restrict__ xsrc,  // [Nsrc,64] fp16 mirror
    const float* __restrict__ xdst,   // [Ndst,64] fp32
    const int* __restrict__ rowptr,   // [Ndst]
    const int* __restrict__ rowend,   // [Ndst]
    const int2* __restrict__ pair,    // gapped, dst-sorted
    const float* __restrict__ lew,    // [64]
    const float* __restrict__ leb,    // [64]
    float* __restrict__ oa,           // [Ndst,64]  agg + xdst
    int N)
{
    int wave = threadIdx.x >> 6, lane = threadIdx.x & 63;
    int n = blockIdx.x * 4 + wave;
    if (n >= N) return;

    int start = __builtin_amdgcn_readfirstlane(rowptr[n]);
    int end   = __builtin_amdgcn_readfirstlane(rowend[n]);
    float lw = lew[lane], lb = leb[lane];
    float xd = xdst[(size_t)n * 64 + lane];   // independent: issue early

    float den = 0.0f, num = 0.0f;
    int j = start;

    if (j + 8 <= end) {
        int2 pb[8];
#pragma unroll
        for (int c = 0; c < 8; ++c) pb[c] = pair[j + c];

        for (; j + 16 <= end; j += 8) {
            float xv[8];
#pragma unroll
            for (int c = 0; c < 8; ++c)
                xv[c] = __half2float(xsrc[(size_t)pb[c].x * 64 + lane]);
            int2 pn[8];
#pragma unroll
            for (int c = 0; c < 8; ++c) pn[c] = pair[j + 8 + c];
#pragma unroll
            for (int c = 0; c < 8; ++c) {
                float msg = relu_(fmaf(__int_as_float(pb[c].y), lw, xv[c] + lb)) + 1e-7f;
                float e = __expf(msg);
                den += e;
                num = fmaf(e, msg, num);
            }
#pragma unroll
            for (int c = 0; c < 8; ++c) pb[c] = pn[c];
        }
        {   // last full 8 (pairs already in registers)
            float xv[8];
#pragma unroll
            for (int c = 0; c < 8; ++c)
                xv[c] = __half2float(xsrc[(size_t)pb[c].x * 64 + lane]);
#pragma unroll
            for (int c = 0; c < 8; ++c) {
                float msg = relu_(fmaf(__int_as_float(pb[c].y), lw, xv[c] + lb)) + 1e-7f;
                float e = __expf(msg);
                den += e;
                num = fmaf(e, msg, num);
            }
            j += 8;
        }
    }
    for (; j < end; ++j) {
        int2 p = pair[j];
        float xv = __half2float(xsrc[(size_t)p.x * 64 + lane]);
        float msg = relu_(fmaf(__int_as_float(p.y), lw, xv + lb)) + 1e-7f;
        float e = __expf(msg);
        den += e;
        num = fmaf(e, msg, num);
    }

    oa[(size_t)n * 64 + lane] = num / (den + 1e-16f) + xd;
}

// ---------------- MLP + pred head: weights from global (L2-broadcast) ------
// Proven R2 config: TN=40, grid 500. Also writes the fp16 feature mirror.
__global__ __launch_bounds__(256, 4) void mlp_kernel(
    const float* __restrict__ oa,    // [N,64]
    float* __restrict__ feat,        // [N,64]
    __half* __restrict__ feat16,     // [N,64] fp16 mirror
    const float* __restrict__ w1,    // [64,128]
    const float* __restrict__ b1,    // [128]
    const float* __restrict__ w2,    // [128,64]
    const float* __restrict__ b2,    // [64]
    const float* __restrict__ pw1,   // [64,64]
    const float* __restrict__ pb1,   // [64]
    const float* __restrict__ pw2,   // [64]
    const float* __restrict__ pb2,   // [1]
    float* __restrict__ outp,
    int N, int layer)
{
    __shared__ float act[TN][68];
    __shared__ float hid[TN][132];
    __shared__ float b1s[128];
    __shared__ float b2s[64];
    __shared__ float pb1s[64];
    __shared__ float pw2s[64];

    int tid = threadIdx.x;
    if (tid < 128) b1s[tid] = b1[tid];
    if (tid < 64) { b2s[tid] = b2[tid]; pb1s[tid] = pb1[tid]; pw2s[tid] = pw2[tid]; }
    float pb2v = pb2[0];

    int o4 = (tid & 31) * 4;
    int o2 = (tid & 31) * 2;
    int n5 = (tid >> 5) * 5;
    __syncthreads();

    int ntiles = N / TN;
    for (int tile = blockIdx.x; tile < ntiles; tile += gridDim.x) {
        int base = tile * TN;
        {
            const float4* g4 = (const float4*)(oa + (size_t)base * 64);
            for (int i = tid; i < TN * 16; i += 256)
                *(float4*)&act[i >> 4][(i & 15) * 4] = g4[i];
        }
        __syncthreads();

        {
            float acc[5][4];
#pragma unroll
            for (int i = 0; i < 5; ++i)
#pragma unroll
                for (int q = 0; q < 4; ++q) acc[i][q] = b1s[o4 + q];
#pragma unroll 2
            for (int k = 0; k < 64; k += 4) {
                float4 a[5];
#pragma unroll
                for (int i = 0; i < 5; ++i) a[i] = *(const float4*)&act[n5 + i][k];
                float4 w0 = *(const float4*)&w1[(k + 0) * 128 + o4];
                float4 wq1 = *(const float4*)&w1[(k + 1) * 128 + o4];
                float4 wq2 = *(const float4*)&w1[(k + 2) * 128 + o4];
                float4 wq3 = *(const float4*)&w1[(k + 3) * 128 + o4];
#pragma unroll
                for (int i = 0; i < 5; ++i) {
                    acc[i][0] = fmaf(a[i].x, w0.x, acc[i][0]);
                    acc[i][1] = fmaf(a[i].x, w0.y, acc[i][1]);
                    acc[i][2] = fmaf(a[i].x, w0.z, acc[i][2]);
                    acc[i][3] = fmaf(a[i].x, w0.w, acc[i][3]);
                    acc[i][0] = fmaf(a[i].y, wq1.x, acc[i][0]);
                    acc[i][1] = fmaf(a[i].y, wq1.y, acc[i][1]);
                    acc[i][2] = fmaf(a[i].y, wq1.z, acc[i][2]);
                    acc[i][3] = fmaf(a[i].y, wq1.w, acc[i][3]);
                    acc[i][0] = fmaf(a[i].z, wq2.x, acc[i][0]);
                    acc[i][1] = fmaf(a[i].z, wq2.y, acc[i][1]);
                    acc[i][2] = fmaf(a[i].z, wq2.z, acc[i][2]);
                    acc[i][3] = fmaf(a[i].z, wq2.w, acc[i][3]);
                    acc[i][0] = fmaf(a[i].w, wq3.x, acc[i][0]);
                    acc[i][1] = fmaf(a[i].w, wq3.y, acc[i][1]);
                    acc[i][2] = fmaf(a[i].w, wq3.z, acc[i][2]);
                    acc[i][3] = fmaf(a[i].w, wq3.w, acc[i][3]);
                }
            }
#pragma unroll
            for (int i = 0; i < 5; ++i) {
                float4 h4 = make_float4(relu_(acc[i][0]), relu_(acc[i][1]),
                                        relu_(acc[i][2]), relu_(acc[i][3]));
                *(float4*)&hid[n5 + i][o4] = h4;
            }
        }
        __syncthreads();

        {
            float acc[5][2];
#pragma unroll
            for (int i = 0; i < 5; ++i) { acc[i][0] = b2s[o2]; acc[i][1] = b2s[o2 + 1]; }
#pragma unroll 2
            for (int k = 0; k < 128; k += 4) {
                float4 a[5];
#pragma unroll
                for (int i = 0; i < 5; ++i) a[i] = *(const float4*)&hid[n5 + i][k];
                float2 w0 = *(const float2*)&w2[(k + 0) * 64 + o2];
                float2 wq1 = *(const float2*)&w2[(k + 1) * 64 + o2];
                float2 wq2 = *(const float2*)&w2[(k + 2) * 64 + o2];
                float2 wq3 = *(const float2*)&w2[(k + 3) * 64 + o2];
#pragma unroll
                for (int i = 0; i < 5; ++i) {
                    acc[i][0] = fmaf(a[i].x, w0.x, acc[i][0]);
                    acc[i][1] = fmaf(a[i].x, w0.y, acc[i][1]);
                    acc[i][0] = fmaf(a[i].y, wq1.x, acc[i][0]);
                    acc[i][1] = fmaf(a[i].y, wq1.y, acc[i][1]);
                    acc[i][0] = fmaf(a[i].z, wq2.x, acc[i][0]);
                    acc[i][1] = fmaf(a[i].z, wq2.y, acc[i][1]);
                    acc[i][0] = fmaf(a[i].w, wq3.x, acc[i][0]);
                    acc[i][1] = fmaf(a[i].w, wq3.y, acc[i][1]);
                }
            }
#pragma unroll
            for (int i = 0; i < 5; ++i) {
                float2 r2 = make_float2(acc[i][0], acc[i][1]);
                *(float2*)&feat[(size_t)(base + n5 + i) * 64 + o2] = r2;
                *(__half2*)&feat16[(size_t)(base + n5 + i) * 64 + o2] =
                    __floats2half2_rn(r2.x, r2.y);
                *(float2*)&act[n5 + i][o2] = r2;
            }
        }
        __syncthreads();

        {
            float acc[5][2];
#pragma unroll
            for (int i = 0; i < 5; ++i) { acc[i][0] = pb1s[o2]; acc[i][1] = pb1s[o2 + 1]; }
#pragma unroll 2
            for (int k = 0; k < 64; k += 4) {
                float4 a[5];
#pragma unroll
                for (int i = 0; i < 5; ++i) a[i] = *(const float4*)&act[n5 + i][k];
                float2 w0 = *(const float2*)&pw1[(k + 0) * 64 + o2];
                float2 wq1 = *(const float2*)&pw1[(k + 1) * 64 + o2];
                float2 wq2 = *(const float2*)&pw1[(k + 2) * 64 + o2];
                float2 wq3 = *(const float2*)&pw1[(k + 3) * 64 + o2];
#pragma unroll
                for (int i = 0; i < 5; ++i) {
                    acc[i][0] = fmaf(a[i].x, w0.x, acc[i][0]);
                    acc[i][1] = fmaf(a[i].x, w0.y, acc[i][1]);
                    acc[i][0] = fmaf(a[i].y, wq1.x, acc[i][0]);
                    acc[i][1] = fmaf(a[i].y, wq1.y, acc[i][1]);
                    acc[i][0] = fmaf(a[i].z, wq2.x, acc[i][0]);
                    acc[i][1] = fmaf(a[i].z, wq2.y, acc[i][1]);
                    acc[i][0] = fmaf(a[i].w, wq3.x, acc[i][0]);
                    acc[i][1] = fmaf(a[i].w, wq3.y, acc[i][1]);
                }
            }
            float pw2a = pw2s[o2], pw2b = pw2s[o2 + 1];
            float ps[5];
#pragma unroll
            for (int i = 0; i < 5; ++i)
                ps[i] = relu_(acc[i][0]) * pw2a + relu_(acc[i][1]) * pw2b;
#pragma unroll
            for (int msk = 16; msk >= 1; msk >>= 1) {
#pragma unroll
                for (int i = 0; i < 5; ++i)
                    ps[i] += __shfl_xor(ps[i], msk, 64);
            }
            if ((tid & 31) == 0) {
#pragma unroll
                for (int i = 0; i < 5; ++i)
                    outp[(size_t)(base + n5 + i) * NLAYER + layer] = ps[i] + pb2v;
            }
        }
        __syncthreads();
    }
}

extern "C" void kernel_launch(void* const* d_in, const int* in_sizes, int n_in,
                              void* d_out, int out_size, void* d_ws, size_t ws_size,
                              hipStream_t stream)
{
    const float* x_vals   = (const float*)d_in[0];
    const float* x_cons   = (const float*)d_in[1];
    const float* pe_vals  = (const float*)d_in[2];
    const float* pe_cons  = (const float*)d_in[3];
    const int*   ei_v2c   = (const int*)d_in[4];   // [2,E]
    const int*   ei_c2v   = (const int*)d_in[5];   // [2,E]
    const float* ew_v2c   = (const float*)d_in[6]; // [E,1]
    const float* ew_c2v   = (const float*)d_in[7];
    const float* enc_vals_w = (const float*)d_in[8];
    const float* enc_vals_b = (const float*)d_in[9];
    const float* pe_vals_w1 = (const float*)d_in[10];
    const float* pe_vals_b1 = (const float*)d_in[11];
    const float* pe_vals_w2 = (const float*)d_in[12];
    const float* pe_vals_b2 = (const float*)d_in[13];
    const float* enc_cons_w = (const float*)d_in[14];
    const float* enc_cons_b = (const float*)d_in[15];
    const float* pe_cons_w1 = (const float*)d_in[16];
    const float* pe_cons_b1 = (const float*)d_in[17];
    const float* pe_cons_w2 = (const float*)d_in[18];
    const float* pe_cons_b2 = (const float*)d_in[19];
    const float* v2c_edge_w = (const float*)d_in[20]; // [NL,1,64]
    const float* v2c_edge_b = (const float*)d_in[21]; // [NL,64]
    const float* v2c_w1     = (const float*)d_in[22]; // [NL,64,128]
    const float* v2c_b1     = (const float*)d_in[23]; // [NL,128]
    const float* v2c_w2     = (const float*)d_in[24]; // [NL,128,64]
    const float* v2c_b2     = (const float*)d_in[25]; // [NL,64]
    const float* c2v_edge_w = (const float*)d_in[26];
    const float* c2v_edge_b = (const float*)d_in[27];
    const float* c2v_w1     = (const float*)d_in[28];
    const float* c2v_b1     = (const float*)d_in[29];
    const float* c2v_w2     = (const float*)d_in[30];
    const float* c2v_b2     = (const float*)d_in[31];
    const float* pred_vals_w1 = (const float*)d_in[32];
    const float* pred_vals_b1 = (const float*)d_in[33];
    const float* pred_vals_w2 = (const float*)d_in[34];
    const float* pred_vals_b2 = (const float*)d_in[35];
    const float* pred_cons_w1 = (const float*)d_in[36];
    const float* pred_cons_b1 = (const float*)d_in[37];
    const float* pred_cons_w2 = (const float*)d_in[38];
    const float* pred_cons_b2 = (const float*)d_in[39];

    float* out = (float*)d_out;
    float* out_c = out + (size_t)NVN * NLAYER;

    const size_t NF = (size_t)NVN * 64;

    // Workspace layout (pair/stage are gapped: NB bins x CAP entries)
    float* ws     = (float*)d_ws;
    float* feat_v = ws;                 // NF
    float* feat_c = feat_v + NF;        // NF
    float* oa     = feat_c + NF;        // NF
    int2* v2c_pair  = (int2*)(oa + NF);        // NBCAP
    int2* c2v_pair  = v2c_pair + NBCAP;        // NBCAP
    int2* v2c_stage = c2v_pair + NBCAP;        // NBCAP
    int2* c2v_stage = v2c_stage + NBCAP;       // NBCAP
    __half* feat16_v = (__half*)(c2v_stage + NBCAP);   // NF halfs
    __half* feat16_c = feat16_v + NF;                  // NF halfs
    int* ip = (int*)(feat16_c + NF);
    int* v2c_bincur  = ip; ip += NB;
    int* c2v_bincur  = ip; ip += NB;
    int* v2c_rowptr  = ip; ip += NCN;
    int* v2c_rowend  = ip; ip += NCN;
    int* c2v_rowptr  = ip; ip += NVN;
    int* c2v_rowend  = ip; ip += NVN;

    const int p1b = (NE + P1E - 1) / P1E;   // 245

    // CSR build (single-pass binning: no histogram/scan passes)
    bininit_kernel<<<1, 256, 0, stream>>>(v2c_bincur, c2v_bincur);
    scatter_p1_kernel<<<p1b, 256, 0, stream>>>(
        ei_v2c, ew_v2c, v2c_bincur, v2c_stage,
        ei_c2v, ew_c2v, c2v_bincur, c2v_stage);
    scatter_p2_kernel<<<2 * NB, 1024, 0, stream>>>(
        v2c_bincur, v2c_stage, v2c_rowptr, v2c_rowend, v2c_pair,
        c2v_bincur, c2v_stage, c2v_rowptr, c2v_rowend, c2v_pair);

    // Encoders
    encode2_kernel<<<(NVN + 3) / 4 + (NCN + 3) / 4, 256, 0, stream>>>(
        x_vals, pe_vals, enc_vals_w, enc_vals_b,
        pe_vals_w1, pe_vals_b1, pe_vals_w2, pe_vals_b2,
        x_cons, pe_cons, enc_cons_w, enc_cons_b,
        pe_cons_w1, pe_cons_b1, pe_cons_w2, pe_cons_b2,
        feat_v, feat_c, feat16_v, feat16_c);

    for (int i = 0; i < NLAYER; ++i) {
        // v2c: src = vals (fp16 mirror), dst = cons
        edge_agg_kernel<<<(NCN + 3) / 4, 256, 0, stream>>>(
            feat16_v, feat_c, v2c_rowptr, v2c_rowend, v2c_pair,
            v2c_edge_w + (size_t)i * HID, v2c_edge_b + (size_t)i * HID,
            oa, NCN);
        mlp_kernel<<<NCN / TN, 256, 0, stream>>>(
            oa, feat_c, feat16_c,
            v2c_w1 + (size_t)i * 8192, v2c_b1 + (size_t)i * 128,
            v2c_w2 + (size_t)i * 8192, v2c_b2 + (size_t)i * 64,
            pred_cons_w1, pred_cons_b1, pred_cons_w2, pred_cons_b2,
            out_c, NCN, i);
        // c2v: src = cons (updated fp16 mirror), dst = vals
        edge_agg_kernel<<<(NVN + 3) / 4, 256, 0, stream>>>(
            feat16_c, feat_v, c2v_rowptr, c2v_rowend, c2v_pair,
            c2v_edge_w + (size_t)i * HID, c2v_edge_b + (size_t)i * HID,
            oa, NVN);
        mlp_kernel<<<NVN / TN, 256, 0, stream>>>(
            oa, feat_v, feat16_v,
            c2v_w1 + (size_t)i * 8192, c2v_b1 + (size_t)i * 128,
            c2v_w2 + (size_t)i * 8192, c2v_b2 + (size_t)i * 64,
            pred_vals_w1, pred_vals_b1, pred_vals_w2, pred_vals_b2,
            out, NVN, i);
    }
}